// Round 17
// baseline (1287.920 us; speedup 1.0000x reference)
//
#include <hip/hip_runtime.h>
#include <cstdint>

typedef _Float16 half2_t __attribute__((ext_vector_type(2)));
typedef _Float16 half8_t __attribute__((ext_vector_type(8)));
typedef float    floatx4 __attribute__((ext_vector_type(4)));

// ---------------- workspace layout (bytes) ----------------
#define OFF_BIAS  0ull
#define SZ_BIAS   (1536ull*4)                  // b_ih + b_hh(r,z) folded, f32
#define OFF_GI    6144ull                      // gi f16 [2][32768][768] (~100.7 MB)

// ---------------- prep: bias fold only (verified) ----------------
__global__ void k_prep(const float* __restrict__ bih1, const float* __restrict__ bih2,
                       const float* __restrict__ bhh1, const float* __restrict__ bhh2,
                       float* __restrict__ biascat) {
    int q3 = blockIdx.x * 256 + threadIdx.x;
    if (q3 < 1536) {
        // fold b_ih (all gates) + b_hh (r,z only; n-gate's b_hh is inside r*(...))
        int dir = q3 >= 768;  int j = q3 - dir*768;
        const float* bi = dir ? bih2 : bih1;
        const float* bh = dir ? bhh2 : bhh1;
        biascat[q3] = bi[j] + (j < 512 ? bh[j] : 0.f);
    }
}

// ---------------- shared helper (verified) ----------------
__device__ __forceinline__ half8_t cvt8(float4 a, float4 b) {
    half8_t r;
    r[0] = (_Float16)a.x; r[1] = (_Float16)a.y; r[2] = (_Float16)a.z; r[3] = (_Float16)a.w;
    r[4] = (_Float16)b.x; r[5] = (_Float16)b.y; r[6] = (_Float16)b.z; r[7] = (_Float16)b.w;
    return r;
}

// ---------------- gi GEMM (verified, source-identical) ----------------
__global__ __launch_bounds__(256) void k_gemm(const float* __restrict__ x,
                                              const float* __restrict__ Wih1,
                                              const float* __restrict__ Wih2,
                                              const float* __restrict__ bias,
                                              _Float16* __restrict__ gi) {
    __shared__ __align__(16) _Float16 As[128*32];
    __shared__ __align__(16) _Float16 Bs[256*32];
    const int tid = threadIdx.x;
    const int m0 = blockIdx.x * 128;
    const int n0 = blockIdx.y * 256;
    const int lane = tid & 63, wave = tid >> 6;
    const int wr = wave >> 1, wc = wave & 1;
    floatx4 acc[4][8];
#pragma unroll
    for (int i = 0; i < 4; ++i)
#pragma unroll
        for (int j = 0; j < 8; ++j) acc[i][j] = (floatx4)0.f;

    const float* Wsrc = (n0 < 768) ? Wih1 : Wih2;
    const int nl = (n0 < 768) ? n0 : (n0 - 768);
    const int ar = tid >> 1, ah = (tid & 1) * 16;
    const float* Ag = x + (size_t)(m0 + ar)*512 + ah;
    const float* Bg = Wsrc + (size_t)(nl + tid)*512;
    _Float16* Aw = As + ar*32 + ah;
    _Float16* Bw = Bs + tid*32;
    const int aoff = (wr*64  + (lane & 15))*32 + (lane >> 4)*8;
    const int boff = (wc*128 + (lane & 15))*32 + (lane >> 4)*8;

    for (int kt = 0; kt < 16; ++kt) {
        const int ko = kt*32;
        float4 a0 = *(const float4*)(Ag + ko);
        float4 a1 = *(const float4*)(Ag + ko + 4);
        float4 a2 = *(const float4*)(Ag + ko + 8);
        float4 a3 = *(const float4*)(Ag + ko + 12);
        float4 b0 = *(const float4*)(Bg + ko);
        float4 b1 = *(const float4*)(Bg + ko + 4);
        float4 b2 = *(const float4*)(Bg + ko + 8);
        float4 b3 = *(const float4*)(Bg + ko + 12);
        float4 b4 = *(const float4*)(Bg + ko + 16);
        float4 b5 = *(const float4*)(Bg + ko + 20);
        float4 b6 = *(const float4*)(Bg + ko + 24);
        float4 b7 = *(const float4*)(Bg + ko + 28);
        __syncthreads();
        *(half8_t*)(Aw)      = cvt8(a0, a1);
        *(half8_t*)(Aw + 8)  = cvt8(a2, a3);
        *(half8_t*)(Bw)      = cvt8(b0, b1);
        *(half8_t*)(Bw + 8)  = cvt8(b2, b3);
        *(half8_t*)(Bw + 16) = cvt8(b4, b5);
        *(half8_t*)(Bw + 24) = cvt8(b6, b7);
        __syncthreads();
        half8_t af[4], bf[8];
#pragma unroll
        for (int f = 0; f < 4; ++f) af[f] = *(const half8_t*)(As + aoff + f*512);
#pragma unroll
        for (int f = 0; f < 8; ++f) bf[f] = *(const half8_t*)(Bs + boff + f*512);
#pragma unroll
        for (int i = 0; i < 4; ++i)
#pragma unroll
            for (int j = 0; j < 8; ++j)
                acc[i][j] = __builtin_amdgcn_mfma_f32_16x16x32_f16(af[i], bf[j], acc[i][j], 0, 0, 0);
    }
#pragma unroll
    for (int i = 0; i < 4; ++i) {
#pragma unroll
        for (int j = 0; j < 8; ++j) {
            int col = n0 + wc*128 + j*16 + (lane & 15);
            float bv = bias[col];
            int dir = col >= 768;
            size_t gib = (size_t)dir * 25165824ull + (size_t)(col - dir*768);
#pragma unroll
            for (int q = 0; q < 4; ++q) {
                int row = m0 + wr*64 + i*16 + (lane >> 4)*4 + q;
                gi[gib + (size_t)row*768] = (_Float16)(acc[i][j][q] + bv);
            }
        }
    }
}

// ---------------- recurrent kernel: 1 WG per (direction, batch-PAIR) ----------------
// R17: B-tile 2. 64 WGs; each thread's W quad (spilled or not) is loaded once
// per kk and feeds BOTH batches' dots (12 w-values x 2 uses, adjacent). Halves
// aggregate W-restream traffic (was ~39 TB/s = at the L2 ceiling). Inner dot,
// W init, gate math, barriers = R7-verified.
#define FDOT2(w_, h_, acc_) __builtin_amdgcn_fdot2(__builtin_bit_cast(half2_t,(w_)), (h_), (acc_), false)
#define LBAR()  do { asm volatile("s_waitcnt lgkmcnt(0)" ::: "memory"); \
                     __builtin_amdgcn_s_barrier(); } while (0)

__global__ __launch_bounds__(512) void k_rnn(const float* __restrict__ Whh1,
                                             const float* __restrict__ Whh2,
                                             const _Float16* __restrict__ gi,
                                             const float* __restrict__ mask,
                                             const float* __restrict__ bhh1,
                                             const float* __restrict__ bhh2,
                                             float* __restrict__ outp) {
    __shared__ __align__(16) _Float16 hs16[512];     // h f16: [bb][c]
    __shared__ float part[1536];                     // kh=1 partials: [bb][gate][c]
    const int tid = threadIdx.x;
    const int bid = blockIdx.x;                      // 0..63
    const int dir = bid >> 5;
    const int b0  = (bid & 31) * 2;                  // batches b0, b0+1
    const int c  = tid & 255;                        // column this thread owns
    const int kh = tid >> 8;                         // K half

    // W_hh rows {c, c+256, c+512}, k in [kh*128, kh*128+128), packed f16x2 (R7).
    const float* W = dir ? Whh2 : Whh1;              // (768, 256) row-major
    unsigned int w[192];
#pragma unroll
    for (int a = 0; a < 3; ++a) {
        const float* wrow = W + (size_t)(c + a*256)*256 + kh*128;
#pragma unroll
        for (int qq = 0; qq < 64; ++qq) {
            float2 f = *(const float2*)(wrow + 2*qq);
            half2_t hp = {(_Float16)f.x, (_Float16)f.y};
            w[a*64 + qq] = __builtin_bit_cast(unsigned int, hp);
        }
    }
    const float bhn = (dir ? bhh2 : bhh1)[512 + c];

    hs16[tid] = (_Float16)0.f;                       // both batches (512 entries)
    float h_c0 = 0.f, h_c1 = 0.f;
    __syncthreads();

    const _Float16* gb = gi + (size_t)dir * 25165824ull + c;
    const _Float16* hrd0 = hs16 + (kh << 7);         // batch0 K-half base
    const _Float16* hrd1 = hs16 + 256 + (kh << 7);   // batch1 K-half base

#pragma unroll 1
    for (int s = 0; s < 512; ++s) {
        const int t = dir ? (511 - s) : s;
        float g00 = 0.f, g01 = 0.f, g02 = 0.f, mv0 = 0.f;
        float g10 = 0.f, g11 = 0.f, g12 = 0.f, mv1 = 0.f;
        if (tid < 256) {
            const _Float16* gp = gb + (size_t)(t*64 + b0)*768;
            g00 = (float)gp[0];    g01 = (float)gp[256];       g02 = (float)gp[512];
            g10 = (float)gp[768];  g11 = (float)gp[768+256];   g12 = (float)gp[768+512];
            mv0 = mask[t*64 + b0];
            mv1 = mask[t*64 + b0 + 1];
        }
        // shared-W dots: per kk load 12 w once, feed both batches (24 fdot2)
        float x0 = 0.f, x1 = 0.f, x2 = 0.f;          // batch0 gates (chain A)
        float y0 = 0.f, y1 = 0.f, y2 = 0.f;          // batch0 gates (chain B)
        float u0 = 0.f, u1 = 0.f, u2 = 0.f;          // batch1 gates (chain A)
        float v0 = 0.f, v1 = 0.f, v2 = 0.f;          // batch1 gates (chain B)
#pragma unroll
        for (int kk = 0; kk < 16; ++kk) {
            half8_t ha = *(const half8_t*)(hrd0 + (kk << 3));  // broadcast reads
            half8_t hb = *(const half8_t*)(hrd1 + (kk << 3));
            half2_t a0p = {ha[0], ha[1]}, a1p = {ha[2], ha[3]};
            half2_t a2p = {ha[4], ha[5]}, a3p = {ha[6], ha[7]};
            half2_t b0p = {hb[0], hb[1]}, b1p = {hb[2], hb[3]};
            half2_t b2p = {hb[4], hb[5]}, b3p = {hb[6], hb[7]};
            const int q = kk << 2;
            unsigned int w0 = w[q+0], w1 = w[q+1], w2 = w[q+2], w3 = w[q+3];
            x0 = FDOT2(w0, a0p, x0);  u0 = FDOT2(w0, b0p, u0);
            y0 = FDOT2(w1, a1p, y0);  v0 = FDOT2(w1, b1p, v0);
            x0 = FDOT2(w2, a2p, x0);  u0 = FDOT2(w2, b2p, u0);
            y0 = FDOT2(w3, a3p, y0);  v0 = FDOT2(w3, b3p, v0);
            unsigned int z0 = w[64+q+0], z1 = w[64+q+1], z2 = w[64+q+2], z3 = w[64+q+3];
            x1 = FDOT2(z0, a0p, x1);  u1 = FDOT2(z0, b0p, u1);
            y1 = FDOT2(z1, a1p, y1);  v1 = FDOT2(z1, b1p, v1);
            x1 = FDOT2(z2, a2p, x1);  u1 = FDOT2(z2, b2p, u1);
            y1 = FDOT2(z3, a3p, y1);  v1 = FDOT2(z3, b3p, v1);
            unsigned int n0 = w[128+q+0], n1 = w[128+q+1], n2 = w[128+q+2], n3 = w[128+q+3];
            x2 = FDOT2(n0, a0p, x2);  u2 = FDOT2(n0, b0p, u2);
            y2 = FDOT2(n1, a1p, y2);  v2 = FDOT2(n1, b1p, v2);
            x2 = FDOT2(n2, a2p, x2);  u2 = FDOT2(n2, b2p, u2);
            y2 = FDOT2(n3, a3p, y2);  v2 = FDOT2(n3, b3p, v2);
        }
        x0 += y0; x1 += y1; x2 += y2;
        u0 += v0; u1 += v1; u2 += v2;
        if (tid >= 256) {
            part[c]        = x0; part[256 + c]  = x1; part[512 + c]  = x2;
            part[768 + c]  = u0; part[1024 + c] = u1; part[1280 + c] = u2;
        }
        LBAR();                                      // partials visible; hs16 reads done
        if (tid < 256) {
            // ---- batch 0 ----
            float ghr = x0 + part[c];
            float ghz = x1 + part[256 + c];
            float ghn = x2 + part[512 + c];
            float r = 1.f / (1.f + __expf(-(g00 + ghr)));
            float z = 1.f / (1.f + __expf(-(g01 + ghz)));
            float tt = g02 + r * (ghn + bhn);
            float ea = __expf(-2.f * fabsf(tt));
            float nt = (1.f - ea) / (1.f + ea);
            nt = (tt < 0.f) ? -nt : nt;
            float ht = (1.f - z) * nt + z * h_c0;
            float hm = mv0 * ht + (1.f - mv0) * h_c0;
            h_c0 = hm;
            hs16[c] = (_Float16)hm;
            outp[(size_t)(t*64 + b0)*512 + dir*256 + c] = mv0 * ht;
            // ---- batch 1 ----
            ghr = u0 + part[768 + c];
            ghz = u1 + part[1024 + c];
            ghn = u2 + part[1280 + c];
            r = 1.f / (1.f + __expf(-(g10 + ghr)));
            z = 1.f / (1.f + __expf(-(g11 + ghz)));
            tt = g12 + r * (ghn + bhn);
            ea = __expf(-2.f * fabsf(tt));
            nt = (1.f - ea) / (1.f + ea);
            nt = (tt < 0.f) ? -nt : nt;
            ht = (1.f - z) * nt + z * h_c1;
            hm = mv1 * ht + (1.f - mv1) * h_c1;
            h_c1 = hm;
            hs16[256 + c] = (_Float16)hm;
            outp[(size_t)(t*64 + b0 + 1)*512 + dir*256 + c] = mv1 * ht;
        }
        LBAR();                                      // hs16 visible for next step
    }
    if (tid < 256) {
        outp[16777216u + dir*16384 + b0*256 + c]       = h_c0;
        outp[16777216u + dir*16384 + (b0+1)*256 + c]   = h_c1;
    }
}

// ---------------- launch ----------------
extern "C" void kernel_launch(void* const* d_in, const int* in_sizes, int n_in,
                              void* d_out, int out_size, void* d_ws, size_t ws_size,
                              hipStream_t stream) {
    const float* x    = (const float*)d_in[0];
    const float* mask = (const float*)d_in[1];
    const float* Wih1 = (const float*)d_in[2];
    const float* Whh1 = (const float*)d_in[3];
    const float* bih1 = (const float*)d_in[4];
    const float* bhh1 = (const float*)d_in[5];
    const float* Wih2 = (const float*)d_in[6];
    const float* Whh2 = (const float*)d_in[7];
    const float* bih2 = (const float*)d_in[8];
    const float* bhh2 = (const float*)d_in[9];
    char* ws = (char*)d_ws;
    float* biascat = (float*)(ws + OFF_BIAS);
    _Float16* gi   = (_Float16*)(ws + OFF_GI);
    float* outp = (float*)d_out;

    hipLaunchKernelGGL(k_prep, dim3(6), dim3(256), 0, stream,
                       bih1, bih2, bhh1, bhh2, biascat);
    hipLaunchKernelGGL(k_gemm, dim3(256, 6), dim3(256), 0, stream, x, Wih1, Wih2, biascat, gi);
    hipLaunchKernelGGL(k_rnn, dim3(64), dim3(512), 0, stream,
                       Whh1, Whh2, gi, mask, bhh1, bhh2, outp);
}